// Round 5
// baseline (633.738 us; speedup 1.0000x reference)
//
#include <hip/hip_runtime.h>

typedef unsigned short u16;
typedef __bf16 bf16x8 __attribute__((ext_vector_type(8)));
typedef short s16x4 __attribute__((ext_vector_type(4)));
typedef float f32x4 __attribute__((ext_vector_type(4)));

#define S_LEN 2048
#define NHEAD 16
#define QHEAD 192
#define EPS 1e-6f
#define ATTN_SCALE 0.07216878364870323f   /* 192^-0.5 */
#define QSCALE_LOG2E 0.10412011228586118f /* ATTN_SCALE * log2(e) */

__device__ __forceinline__ u16 f2bf(float f) {
    unsigned u = __builtin_bit_cast(unsigned, f);
    u = (u + 0x7FFFu + ((u >> 16) & 1u)) >> 16;
    return (u16)u;
}
__device__ __forceinline__ float bf2f(u16 h) {
    unsigned u = ((unsigned)h) << 16;
    return __builtin_bit_cast(float, u);
}

__device__ __forceinline__ void gl_lds16(const u16* g, u16* l) {
    __builtin_amdgcn_global_load_lds(
        (const __attribute__((address_space(1))) unsigned int*)g,
        (__attribute__((address_space(3))) unsigned int*)l,
        16, 0, 0);
}

#if defined(__has_builtin) && __has_builtin(__builtin_amdgcn_mfma_f32_16x16x16bf16_1k)
__device__ __forceinline__ f32x4 mfma16(s16x4 a, s16x4 b, f32x4 c) {
    return __builtin_amdgcn_mfma_f32_16x16x16bf16_1k(a, b, c, 0, 0, 0);
}
#else
__device__ __forceinline__ f32x4 mfma16(s16x4 a, s16x4 b, f32x4 c) {
    asm volatile("v_mfma_f32_16x16x16_bf16 %0, %1, %2, %0"
                 : "+v"(c) : "v"(a), "v"(b));
    return c;
}
#endif

// ---------------------------------------------------------------------------
// bf16 GEMM:  C[M][N] = A[M][K] @ Bt[N][K]^T   (m97-structure, conflict-free)
// ---------------------------------------------------------------------------
template <int CF32>
__global__ __launch_bounds__(256, 2)
void gemm_bt(const u16* __restrict__ A, const u16* __restrict__ B,
             void* __restrict__ Cv, int K, int lda, int ldb, int ldc)
{
    const int tid = threadIdx.x;
    const int wave = tid >> 6, lane = tid & 63;
    const int q = lane >> 4, r = lane & 15;
    const int tm = blockIdx.y, tn = blockIdx.x;

    __shared__ __align__(16) u16 Al[128 * 32];
    __shared__ __align__(16) u16 Bl[128 * 32];

    const int lr = lane & 15;
    const int lc = (lane >> 4) * 8;
    const u16* ag0 = A + (long)(tm * 128 + wave * 32 + lr) * lda + lc;
    const u16* ag1 = ag0 + 16 * (long)lda;
    const u16* bg0 = B + (long)(tn * 128 + wave * 32 + lr) * ldb + lc;
    const u16* bg1 = bg0 + 16 * (long)ldb;
    u16* al0 = &Al[wave * 1024];
    u16* al1 = &Al[wave * 1024 + 512];
    u16* bl0 = &Bl[wave * 1024];
    u16* bl1 = &Bl[wave * 1024 + 512];

    f32x4 acc[4][4] = {};
    const int cm = (wave >> 1) * 4;
    const int cn = (wave & 1) * 4;

    for (int k0 = 0; k0 < K; k0 += 32) {
        gl_lds16(ag0 + k0, al0);
        gl_lds16(ag1 + k0, al1);
        gl_lds16(bg0 + k0, bl0);
        gl_lds16(bg1 + k0, bl1);
        __syncthreads();
        bf16x8 af[4], bv[4];
        #pragma unroll
        for (int mt = 0; mt < 4; ++mt) af[mt] = *(const bf16x8*)&Al[(cm + mt) * 512 + lane * 8];
        #pragma unroll
        for (int nt = 0; nt < 4; ++nt) bv[nt] = *(const bf16x8*)&Bl[(cn + nt) * 512 + lane * 8];
        #pragma unroll
        for (int mt = 0; mt < 4; ++mt)
            #pragma unroll
            for (int nt = 0; nt < 4; ++nt)
                acc[mt][nt] = __builtin_amdgcn_mfma_f32_16x16x32_bf16(
                    af[mt], bv[nt], acc[mt][nt], 0, 0, 0);
        __syncthreads();
    }

    const int wm = (wave >> 1) * 64, wn = (wave & 1) * 64;
    const int row0 = tm * 128 + wm + q * 4;
    const int col0 = tn * 128 + wn + r;
    if (CF32) {
        float* C = (float*)Cv;
        #pragma unroll
        for (int mt = 0; mt < 4; ++mt)
            #pragma unroll
            for (int i = 0; i < 4; ++i) {
                long rb = (long)(row0 + mt * 16 + i) * ldc + col0;
                #pragma unroll
                for (int nt = 0; nt < 4; ++nt)
                    C[rb + nt * 16] = acc[mt][nt][i];
            }
    } else {
        u16* C = (u16*)Cv;
        #pragma unroll
        for (int mt = 0; mt < 4; ++mt)
            #pragma unroll
            for (int i = 0; i < 4; ++i) {
                long rb = (long)(row0 + mt * 16 + i) * ldc + col0;
                #pragma unroll
                for (int nt = 0; nt < 4; ++nt)
                    C[rb + nt * 16] = f2bf(acc[mt][nt][i]);
            }
    }
}

// ---------------------------------------------------------------------------
// q_b GEMM with fused rope + relayout + exp2-domain pre-scale.
// C logical [2048 s][3072 col]; col -> (h = col/192, d = col%192).
// d < 128: query[h][s][d] = C * QS.  d >= 128: rope pair (even,odd cols) via
// __shfl_xor(.,1); even lane writes 128+i, odd writes 160+i. Rope column
// groups are 64-aligned -> the per-nt branch is wave-uniform.
// ---------------------------------------------------------------------------
__global__ __launch_bounds__(256, 2)
void gemm_qrope(const u16* __restrict__ A, const u16* __restrict__ B,
                u16* __restrict__ query, const int* __restrict__ posid,
                const float* __restrict__ cosb, const float* __restrict__ sinb)
{
    const int K = 1536, lda = 2176, ldb = 1536;
    const int tid = threadIdx.x;
    const int wave = tid >> 6, lane = tid & 63;
    const int q = lane >> 4, r = lane & 15;
    const int tm = blockIdx.y, tn = blockIdx.x;

    __shared__ __align__(16) u16 Al[128 * 32];
    __shared__ __align__(16) u16 Bl[128 * 32];

    const int lr = lane & 15;
    const int lc = (lane >> 4) * 8;
    const u16* ag0 = A + (long)(tm * 128 + wave * 32 + lr) * lda + lc;
    const u16* ag1 = ag0 + 16 * (long)lda;
    const u16* bg0 = B + (long)(tn * 128 + wave * 32 + lr) * ldb + lc;
    const u16* bg1 = bg0 + 16 * (long)ldb;
    u16* al0 = &Al[wave * 1024];
    u16* al1 = &Al[wave * 1024 + 512];
    u16* bl0 = &Bl[wave * 1024];
    u16* bl1 = &Bl[wave * 1024 + 512];

    f32x4 acc[4][4] = {};
    const int cm = (wave >> 1) * 4;
    const int cn = (wave & 1) * 4;

    for (int k0 = 0; k0 < K; k0 += 32) {
        gl_lds16(ag0 + k0, al0);
        gl_lds16(ag1 + k0, al1);
        gl_lds16(bg0 + k0, bl0);
        gl_lds16(bg1 + k0, bl1);
        __syncthreads();
        bf16x8 af[4], bv[4];
        #pragma unroll
        for (int mt = 0; mt < 4; ++mt) af[mt] = *(const bf16x8*)&Al[(cm + mt) * 512 + lane * 8];
        #pragma unroll
        for (int nt = 0; nt < 4; ++nt) bv[nt] = *(const bf16x8*)&Bl[(cn + nt) * 512 + lane * 8];
        #pragma unroll
        for (int mt = 0; mt < 4; ++mt)
            #pragma unroll
            for (int nt = 0; nt < 4; ++nt)
                acc[mt][nt] = __builtin_amdgcn_mfma_f32_16x16x32_bf16(
                    af[mt], bv[nt], acc[mt][nt], 0, 0, 0);
        __syncthreads();
    }

    const int wm = (wave >> 1) * 64, wn = (wave & 1) * 64;
    const int row0 = tm * 128 + wm + q * 4;
    #pragma unroll
    for (int mt = 0; mt < 4; ++mt)
        #pragma unroll
        for (int i = 0; i < 4; ++i) {
            const int row = row0 + mt * 16 + i;
            const int p = posid[row];
            #pragma unroll
            for (int nt = 0; nt < 4; ++nt) {
                const int g = tn * 128 + wn + nt * 16;   // 16-aligned group base
                const int h = g / 192;
                const int dg = g - h * 192;
                float v = acc[mt][nt][i];
                u16* qr = query + ((size_t)h * S_LEN + row) * QHEAD;
                if (dg < 128) {
                    qr[dg + r] = f2bf(v * QSCALE_LOG2E);
                } else {
                    float vp = __shfl_xor(v, 1, 64);
                    int ir = (dg + r - 128) >> 1;
                    int odd = r & 1;
                    int co = p * 64 + odd * 32 + ir;
                    float c = cosb[co], s = sinb[co];
                    float res = odd ? (v * c + vp * s) : (v * c - vp * s);
                    qr[(odd ? 160 : 128) + ir] = f2bf(res * QSCALE_LOG2E);
                }
            }
        }
}

// ---------------------------------------------------------------------------
// Flash attention v5: S^T form, NO split-k. Block = 256 thr (4 waves),
// q-strip 64 (wave w owns 16 q-cols: q0+w*16+r). kv-tile 128.
// Grid (32 strips heavy-first, 16 heads) = 512 blocks; 80KB LDS -> 2
// blocks/CU = 8 waves/CU = 2 waves/SIMD.
// ---------------------------------------------------------------------------
template <int NT>
__device__ __forceinline__ void kv_step5(
    const u16* __restrict__ Kl, const u16* __restrict__ Vl,
    const bf16x8 (&Qf)[6], f32x4 (&Oacc)[8], float& lsum,
    int lane, int quad, int r, int kglob0, int qg, bool maskT)
{
    f32x4 Sacc[NT];
    #pragma unroll
    for (int mtk = 0; mtk < NT; ++mtk) Sacc[mtk] = (f32x4){0.f, 0.f, 0.f, 0.f};
    #pragma unroll
    for (int kc = 0; kc < 6; ++kc)
        #pragma unroll
        for (int mtk = 0; mtk < NT; ++mtk) {
            bf16x8 Ak = *(const bf16x8*)&Kl[(mtk * 6 + kc) * 512 + lane * 8];
            Sacc[mtk] = __builtin_amdgcn_mfma_f32_16x16x32_bf16(
                Ak, Qf[kc], Sacc[mtk], 0, 0, 0);
        }
    #pragma unroll
    for (int kb = 0; kb < NT; ++kb) {
        s16x4 Pf;
        const int kb0 = kglob0 + kb * 16 + quad * 4;
        #pragma unroll
        for (int i = 0; i < 4; ++i) {
            float p = exp2f(Sacc[kb][i]);
            if (maskT && (kb0 + i > qg)) p = 0.f;
            lsum += p;
            Pf[i] = (short)f2bf(p);
        }
        #pragma unroll
        for (int mtd = 0; mtd < 8; ++mtd) {
            s16x4 Av = *(const s16x4*)&Vl[(mtd * 4 + (kb >> 1)) * 512
                         + ((kb & 1) * 2 + (quad >> 1)) * 128 + r * 8 + (quad & 1) * 4];
            Oacc[mtd] = mfma16(Av, Pf, Oacc[mtd]);
        }
    }
}

__global__ __launch_bounds__(256, 2)
void flash_attn(const u16* __restrict__ query, const u16* __restrict__ kvb,
                const u16* __restrict__ kpe, const u16* __restrict__ vt,
                u16* __restrict__ ao)
{
    const int tid = threadIdx.x;
    const int w = tid >> 6, lane = tid & 63;
    const int quad = lane >> 4, r = lane & 15;
    const int j = 31 - (int)blockIdx.x;   // heavy strips first
    const int h = blockIdx.y;
    const int q0 = j * 64;
    const int ntk = (j >> 1) + 1;
    const int mtk_last = ((q0 & 127) + 79) >> 4;   // 4 (even j) or 8 (odd j)

    __shared__ __align__(16) u16 Kl[24576];   // 48KB: 48 chunks (16k x 32d)
    __shared__ __align__(16) u16 Vl[16384];   // 32KB: 32 chunks (16d x 32s)

    const int qg = q0 + w * 16 + r;           // this lane's q column

    bf16x8 Qf[6];
    #pragma unroll
    for (int kc = 0; kc < 6; ++kc)
        Qf[kc] = *(const bf16x8*)(query
            + ((size_t)h * S_LEN + qg) * QHEAD + kc * 32 + quad * 8);

    f32x4 Oacc[8];
    #pragma unroll
    for (int mtd = 0; mtd < 8; ++mtd) Oacc[mtd] = (f32x4){0.f, 0.f, 0.f, 0.f};
    float lsum = 0.f;

    for (int tk = 0; tk < ntk; ++tk) {
        const bool last = (tk == ntk - 1);
        const int me = last ? mtk_last : 8;
        // staging: 80 chunks (48 K + 32 V); wave w does [w*20, w*20+20)
        #pragma unroll
        for (int cc = 0; cc < 20; ++cc) {
            int g = w * 20 + cc;
            if (g < 48) {
                int mtk = g / 6, kc = g % 6;
                if (mtk < me) {
                    int row = tk * 128 + mtk * 16 + r;
                    const u16* src = (kc < 4)
                        ? kvb + (size_t)row * 4096 + h * 256 + kc * 32 + quad * 8
                        : kpe + (size_t)row * 64 + (kc - 4) * 32 + quad * 8;
                    gl_lds16(src, &Kl[g * 512]);
                }
            } else {
                int cv = g - 48, mtd = cv >> 2, sc = cv & 3;
                if (sc < (me >> 1)) {
                    const u16* src = vt + ((size_t)h * 128 + mtd * 16 + r) * 2048
                                     + tk * 128 + sc * 32 + quad * 8;
                    gl_lds16(src, &Vl[cv * 512]);
                }
            }
        }
        __syncthreads();
        if (me == 8)
            kv_step5<8>(Kl, Vl, Qf, Oacc, lsum, lane, quad, r, tk * 128, qg, last);
        else
            kv_step5<4>(Kl, Vl, Qf, Oacc, lsum, lane, quad, r, tk * 128, qg, last);
        __syncthreads();
    }

    // epilogue: reduce l over quads, normalize, write ao[q][h*128+d]
    lsum += __shfl_xor(lsum, 16, 64);
    lsum += __shfl_xor(lsum, 32, 64);
    float inv = 1.0f / lsum;
    #pragma unroll
    for (int mtd = 0; mtd < 8; ++mtd) {
        ushort4 o;
        o.x = f2bf(Oacc[mtd][0] * inv);
        o.y = f2bf(Oacc[mtd][1] * inv);
        o.z = f2bf(Oacc[mtd][2] * inv);
        o.w = f2bf(Oacc[mtd][3] * inv);
        *(ushort4*)(ao + (size_t)qg * 2048 + h * 128 + mtd * 16 + quad * 4) = o;
    }
}

// ---------------------------------------------------------------------------
__global__ __launch_bounds__(256)
void cvt_f32_bf16(const float4* __restrict__ in, ushort4* __restrict__ out, int n4)
{
    int i = blockIdx.x * 256 + threadIdx.x;
    if (i < n4) {
        float4 v = in[i];
        ushort4 o;
        o.x = f2bf(v.x); o.y = f2bf(v.y); o.z = f2bf(v.z); o.w = f2bf(v.w);
        out[i] = o;
    }
}

// all 5 weight transposes in one dispatch. fp32 [K][N] -> bf16 [Npad][K].
struct WT5 {
    const float* src[5];
    u16* dst[5];
    int K[5], Np[5], N[5], start[6];
};
__global__ __launch_bounds__(256)
void wtrans_multi(WT5 t)
{
    __shared__ float tile[32][33];
    int bid = blockIdx.x;
    int seg = 0;
    #pragma unroll
    for (int s = 0; s < 5; ++s)
        if (bid >= t.start[s]) seg = s;
    int local = bid - t.start[seg];
    int ntn = t.Np[seg] >> 5;
    int kt = local / ntn, nt = local - kt * ntn;
    const float* in = t.src[seg];
    u16* out = t.dst[seg];
    int K = t.K[seg], N = t.N[seg];
    int k0 = kt * 32, n0 = nt * 32;
    int tx = threadIdx.x, ty = threadIdx.y;
    #pragma unroll
    for (int jj = 0; jj < 32; jj += 8) {
        int n = n0 + tx;
        tile[ty + jj][tx] = (n < N) ? in[(long)(k0 + ty + jj) * N + n] : 0.0f;
    }
    __syncthreads();
    #pragma unroll
    for (int jj = 0; jj < 32; jj += 8)
        out[(long)(n0 + ty + jj) * K + k0 + tx] = f2bf(tile[tx][ty + jj]);
}

// fused: RMS-norm q_a (cols 0..1535, in place) + RMS-norm c (cols 1536..2047
// -> kvout fp32 / cnb bf16) + k_pe rope (cols 2048..2111 -> kvout / kpe).
__global__ __launch_bounds__(256)
void norm_fused(u16* __restrict__ qkv, const float* __restrict__ q_ln,
                const float* __restrict__ kv_ln, const int* __restrict__ pos_ids,
                const float* __restrict__ cosb, const float* __restrict__ sinb,
                float* __restrict__ kvout, u16* __restrict__ cnb,
                u16* __restrict__ kpe)
{
    const int s = blockIdx.x, tid = threadIdx.x;
    u16* row = qkv + (size_t)s * 2176;
    __shared__ float red1[4], red2[4];
    float s1 = 0.f, s2 = 0.f;
    for (int d = tid; d < 2048; d += 256) {
        float v = bf2f(row[d]); float v2 = v * v;
        if (d < 1536) s1 += v2; else s2 += v2;
    }
    #pragma unroll
    for (int o = 32; o; o >>= 1) { s1 += __shfl_xor(s1, o, 64); s2 += __shfl_xor(s2, o, 64); }
    if ((tid & 63) == 0) { red1[tid >> 6] = s1; red2[tid >> 6] = s2; }
    __syncthreads();
    s1 = red1[0] + red1[1] + red1[2] + red1[3];
    s2 = red2[0] + red2[1] + red2[2] + red2[3];
    const float sc1 = rsqrtf(s1 / 1536.f + EPS);
    const float sc2 = rsqrtf(s2 / 512.f + EPS);
    for (int d = tid; d < 1536; d += 256)
        row[d] = f2bf(bf2f(row[d]) * sc1 * q_ln[d]);
    for (int d = tid; d < 512; d += 256) {
        float v = bf2f(row[1536 + d]) * sc2 * kv_ln[d];
        kvout[(size_t)s * 576 + d] = v;
        cnb[(size_t)s * 512 + d] = f2bf(v);
    }
    if (tid < 32) {
        int p = pos_ids[s];
        float x0 = bf2f(row[2048 + 2 * tid]);
        float x1 = bf2f(row[2048 + 2 * tid + 1]);
        float c1 = cosb[p * 64 + tid], sn1 = sinb[p * 64 + tid];
        float c2 = cosb[p * 64 + 32 + tid], sn2 = sinb[p * 64 + 32 + tid];
        float lo = x0 * c1 - x1 * sn1;
        float hi = x1 * c2 + x0 * sn2;
        kvout[(size_t)s * 576 + 512 + tid] = lo;
        kvout[(size_t)s * 576 + 544 + tid] = hi;
        kpe[(size_t)s * 64 + tid] = f2bf(lo);
        kpe[(size_t)s * 64 + 32 + tid] = f2bf(hi);
    }
}

// kv bf16 [S][4096] value part -> vt bf16 [H*128][S] (transposed)
__global__ __launch_bounds__(256)
void vtrans_k(const u16* __restrict__ kv, u16* __restrict__ vt)
{
    __shared__ u16 tile[32][33];
    int s0 = blockIdx.x * 32, d0 = blockIdx.y * 32, h = blockIdx.z;
    int tx = threadIdx.x, ty = threadIdx.y;
    #pragma unroll
    for (int jj = 0; jj < 32; jj += 8)
        tile[ty + jj][tx] = kv[(long)(s0 + ty + jj) * 4096 + h * 256 + 128 + d0 + tx];
    __syncthreads();
    #pragma unroll
    for (int jj = 0; jj < 32; jj += 8)
        vt[(long)(h * 128 + d0 + ty + jj) * S_LEN + s0 + tx] = tile[tx][ty + jj];
}

// ---------------------------------------------------------------------------
extern "C" void kernel_launch(void* const* d_in, const int* in_sizes, int n_in,
                              void* d_out, int out_size, void* d_ws, size_t ws_size,
                              hipStream_t stream)
{
    const float* x      = (const float*)d_in[0];
    const int*   posid  = (const int*)d_in[2];
    const float* cosb   = (const float*)d_in[3];
    const float* sinb   = (const float*)d_in[4];
    const float* q_a_w  = (const float*)d_in[5];
    const float* q_a_ln = (const float*)d_in[6];
    const float* q_b_w  = (const float*)d_in[7];
    const float* kv_a_w = (const float*)d_in[8];
    const float* kv_a_ln= (const float*)d_in[9];
    const float* kv_b_w = (const float*)d_in[10];
    const float* o_w    = (const float*)d_in[11];

    float* out    = (float*)d_out;
    float* kv_out = out + (size_t)2048 * 2048;

    char* ws = (char*)d_ws;
    size_t off = 0;
    auto alloc = [&](size_t bytes) { char* p = ws + off; off += (bytes + 255) & ~(size_t)255; return p; };
    u16* owt   = (u16*)alloc(2048ULL * 2048 * 2);
    u16* query = (u16*)alloc(16ULL * 2048 * 192 * 2);
    u16* kpe   = (u16*)alloc(2048ULL * 64 * 2);
    u16* kvbuf = (u16*)alloc(2048ULL * 4096 * 2);
    u16* vt    = (u16*)alloc(16ULL * 128 * 2048 * 2);
    u16* ao    = (u16*)alloc(2048ULL * 2048 * 2);
    u16* xb    = (u16*)alloc(2048ULL * 2048 * 2);
    u16* W1    = (u16*)alloc(2176ULL * 2048 * 2);   // [q_a^T ; kv_a^T(pad 640)]
    u16* qbwt  = (u16*)alloc(3072ULL * 1536 * 2);
    u16* kvbwt = (u16*)alloc(4096ULL * 512 * 2);
    u16* qkv_a = (u16*)alloc(2048ULL * 2176 * 2);   // [q_a(1536) | ckv(640)]
    u16* cnb   = (u16*)alloc(2048ULL * 512 * 2);
    (void)ws_size; (void)in_sizes; (void)n_in; (void)out_size;

    dim3 blk(256);
    dim3 tblk(32, 8);

    // 0) input convert + all weight transposes (one dispatch)
    cvt_f32_bf16<<<dim3(4096), blk, 0, stream>>>((const float4*)x, (ushort4*)xb, 2048 * 2048 / 4);
    WT5 t;
    t.src[0] = q_a_w;  t.dst[0] = W1;                  t.K[0] = 2048; t.Np[0] = 1536; t.N[0] = 1536;
    t.src[1] = kv_a_w; t.dst[1] = W1 + 1536ULL * 2048; t.K[1] = 2048; t.Np[1] = 640;  t.N[1] = 576;
    t.src[2] = q_b_w;  t.dst[2] = qbwt;                t.K[2] = 1536; t.Np[2] = 3072; t.N[2] = 3072;
    t.src[3] = kv_b_w; t.dst[3] = kvbwt;               t.K[3] = 512;  t.Np[3] = 4096; t.N[3] = 4096;
    t.src[4] = o_w;    t.dst[4] = owt;                 t.K[4] = 2048; t.Np[4] = 2048; t.N[4] = 2048;
    t.start[0] = 0;
    t.start[1] = t.start[0] + (2048 / 32) * (1536 / 32);
    t.start[2] = t.start[1] + (2048 / 32) * (640 / 32);
    t.start[3] = t.start[2] + (1536 / 32) * (3072 / 32);
    t.start[4] = t.start[3] + (512 / 32) * (4096 / 32);
    t.start[5] = t.start[4] + (2048 / 32) * (2048 / 32);
    wtrans_multi<<<dim3(t.start[5]), tblk, 0, stream>>>(t);

    // 1) [q_a | ckv] = x @ [q_a_w | kv_a_w]; fused norms + k_pe rope
    gemm_bt<0><<<dim3(17, 16), blk, 0, stream>>>(xb, W1, qkv_a, 2048, 2048, 2048, 2176);
    norm_fused<<<dim3(2048), blk, 0, stream>>>(qkv_a, q_a_ln, kv_a_ln, posid, cosb, sinb,
                                               kv_out, cnb, kpe);

    // 2) q = q_a_norm @ q_b_w with fused rope/relayout/scale -> query
    gemm_qrope<<<dim3(24, 16), blk, 0, stream>>>(qkv_a, qbwt, query, posid, cosb, sinb);

    // 3) kv = c_norm @ kv_b_w ; transpose value
    gemm_bt<0><<<dim3(32, 16), blk, 0, stream>>>(cnb, kvbwt, kvbuf, 512, 512, 512, 4096);
    vtrans_k<<<dim3(64, 4, 16), tblk, 0, stream>>>(kvbuf, vt);

    // 4) flash attention (no split-k) -> ao bf16 [S][H*128]
    flash_attn<<<dim3(32, 16), blk, 0, stream>>>(query, kvbuf, kpe, vt, ao);

    // 5) out = ao @ o_w (fp32)
    gemm_bt<1><<<dim3(16, 16), blk, 0, stream>>>(ao, owt, out, 2048, 2048, 2048, 2048);
}

// Round 6
// 533.296 us; speedup vs baseline: 1.1883x; 1.1883x over previous
//
#include <hip/hip_runtime.h>

typedef unsigned short u16;
typedef __bf16 bf16x8 __attribute__((ext_vector_type(8)));
typedef short s16x4 __attribute__((ext_vector_type(4)));
typedef float f32x4 __attribute__((ext_vector_type(4)));

#define S_LEN 2048
#define NHEAD 16
#define QHEAD 192
#define EPS 1e-6f
#define ATTN_SCALE 0.07216878364870323f   /* 192^-0.5 */
#define QSCALE_LOG2E 0.10412011228586118f /* ATTN_SCALE * log2(e) */

__device__ __forceinline__ u16 f2bf(float f) {
    unsigned u = __builtin_bit_cast(unsigned, f);
    u = (u + 0x7FFFu + ((u >> 16) & 1u)) >> 16;
    return (u16)u;
}
__device__ __forceinline__ float bf2f(u16 h) {
    unsigned u = ((unsigned)h) << 16;
    return __builtin_bit_cast(float, u);
}

__device__ __forceinline__ void gl_lds16(const u16* g, u16* l) {
    __builtin_amdgcn_global_load_lds(
        (const __attribute__((address_space(1))) unsigned int*)g,
        (__attribute__((address_space(3))) unsigned int*)l,
        16, 0, 0);
}

#if defined(__has_builtin) && __has_builtin(__builtin_amdgcn_mfma_f32_16x16x16bf16_1k)
__device__ __forceinline__ f32x4 mfma16(s16x4 a, s16x4 b, f32x4 c) {
    return __builtin_amdgcn_mfma_f32_16x16x16bf16_1k(a, b, c, 0, 0, 0);
}
#else
__device__ __forceinline__ f32x4 mfma16(s16x4 a, s16x4 b, f32x4 c) {
    asm volatile("v_mfma_f32_16x16x16_bf16 %0, %1, %2, %0"
                 : "+v"(c) : "v"(a), "v"(b));
    return c;
}
#endif

// ---------------------------------------------------------------------------
// bf16 GEMM:  C[M][N] = A[M][K] @ Bt[N][K]^T   (m97-structure, conflict-free)
// ---------------------------------------------------------------------------
template <int CF32>
__global__ __launch_bounds__(256, 2)
void gemm_bt(const u16* __restrict__ A, const u16* __restrict__ B,
             void* __restrict__ Cv, int K, int lda, int ldb, int ldc)
{
    const int tid = threadIdx.x;
    const int wave = tid >> 6, lane = tid & 63;
    const int q = lane >> 4, r = lane & 15;
    const int tm = blockIdx.y, tn = blockIdx.x;

    __shared__ __align__(16) u16 Al[128 * 32];
    __shared__ __align__(16) u16 Bl[128 * 32];

    const int lr = lane & 15;
    const int lc = (lane >> 4) * 8;
    const u16* ag0 = A + (long)(tm * 128 + wave * 32 + lr) * lda + lc;
    const u16* ag1 = ag0 + 16 * (long)lda;
    const u16* bg0 = B + (long)(tn * 128 + wave * 32 + lr) * ldb + lc;
    const u16* bg1 = bg0 + 16 * (long)ldb;
    u16* al0 = &Al[wave * 1024];
    u16* al1 = &Al[wave * 1024 + 512];
    u16* bl0 = &Bl[wave * 1024];
    u16* bl1 = &Bl[wave * 1024 + 512];

    f32x4 acc[4][4] = {};
    const int cm = (wave >> 1) * 4;
    const int cn = (wave & 1) * 4;

    for (int k0 = 0; k0 < K; k0 += 32) {
        gl_lds16(ag0 + k0, al0);
        gl_lds16(ag1 + k0, al1);
        gl_lds16(bg0 + k0, bl0);
        gl_lds16(bg1 + k0, bl1);
        __syncthreads();
        bf16x8 af[4], bv[4];
        #pragma unroll
        for (int mt = 0; mt < 4; ++mt) af[mt] = *(const bf16x8*)&Al[(cm + mt) * 512 + lane * 8];
        #pragma unroll
        for (int nt = 0; nt < 4; ++nt) bv[nt] = *(const bf16x8*)&Bl[(cn + nt) * 512 + lane * 8];
        #pragma unroll
        for (int mt = 0; mt < 4; ++mt)
            #pragma unroll
            for (int nt = 0; nt < 4; ++nt)
                acc[mt][nt] = __builtin_amdgcn_mfma_f32_16x16x32_bf16(
                    af[mt], bv[nt], acc[mt][nt], 0, 0, 0);
        __syncthreads();
    }

    const int wm = (wave >> 1) * 64, wn = (wave & 1) * 64;
    const int row0 = tm * 128 + wm + q * 4;
    const int col0 = tn * 128 + wn + r;
    if (CF32) {
        float* C = (float*)Cv;
        #pragma unroll
        for (int mt = 0; mt < 4; ++mt)
            #pragma unroll
            for (int i = 0; i < 4; ++i) {
                long rb = (long)(row0 + mt * 16 + i) * ldc + col0;
                #pragma unroll
                for (int nt = 0; nt < 4; ++nt)
                    C[rb + nt * 16] = acc[mt][nt][i];
            }
    } else {
        u16* C = (u16*)Cv;
        #pragma unroll
        for (int mt = 0; mt < 4; ++mt)
            #pragma unroll
            for (int i = 0; i < 4; ++i) {
                long rb = (long)(row0 + mt * 16 + i) * ldc + col0;
                #pragma unroll
                for (int nt = 0; nt < 4; ++nt)
                    C[rb + nt * 16] = f2bf(acc[mt][nt][i]);
            }
    }
}

// ---------------------------------------------------------------------------
// q_b GEMM with fused rope + relayout + exp2-domain pre-scale.
// ---------------------------------------------------------------------------
__global__ __launch_bounds__(256, 2)
void gemm_qrope(const u16* __restrict__ A, const u16* __restrict__ B,
                u16* __restrict__ query, const int* __restrict__ posid,
                const float* __restrict__ cosb, const float* __restrict__ sinb)
{
    const int K = 1536, lda = 2176, ldb = 1536;
    const int tid = threadIdx.x;
    const int wave = tid >> 6, lane = tid & 63;
    const int q = lane >> 4, r = lane & 15;
    const int tm = blockIdx.y, tn = blockIdx.x;

    __shared__ __align__(16) u16 Al[128 * 32];
    __shared__ __align__(16) u16 Bl[128 * 32];

    const int lr = lane & 15;
    const int lc = (lane >> 4) * 8;
    const u16* ag0 = A + (long)(tm * 128 + wave * 32 + lr) * lda + lc;
    const u16* ag1 = ag0 + 16 * (long)lda;
    const u16* bg0 = B + (long)(tn * 128 + wave * 32 + lr) * ldb + lc;
    const u16* bg1 = bg0 + 16 * (long)ldb;
    u16* al0 = &Al[wave * 1024];
    u16* al1 = &Al[wave * 1024 + 512];
    u16* bl0 = &Bl[wave * 1024];
    u16* bl1 = &Bl[wave * 1024 + 512];

    f32x4 acc[4][4] = {};
    const int cm = (wave >> 1) * 4;
    const int cn = (wave & 1) * 4;

    for (int k0 = 0; k0 < K; k0 += 32) {
        gl_lds16(ag0 + k0, al0);
        gl_lds16(ag1 + k0, al1);
        gl_lds16(bg0 + k0, bl0);
        gl_lds16(bg1 + k0, bl1);
        __syncthreads();
        bf16x8 af[4], bv[4];
        #pragma unroll
        for (int mt = 0; mt < 4; ++mt) af[mt] = *(const bf16x8*)&Al[(cm + mt) * 512 + lane * 8];
        #pragma unroll
        for (int nt = 0; nt < 4; ++nt) bv[nt] = *(const bf16x8*)&Bl[(cn + nt) * 512 + lane * 8];
        #pragma unroll
        for (int mt = 0; mt < 4; ++mt)
            #pragma unroll
            for (int nt = 0; nt < 4; ++nt)
                acc[mt][nt] = __builtin_amdgcn_mfma_f32_16x16x32_bf16(
                    af[mt], bv[nt], acc[mt][nt], 0, 0, 0);
        __syncthreads();
    }

    const int wm = (wave >> 1) * 64, wn = (wave & 1) * 64;
    const int row0 = tm * 128 + wm + q * 4;
    #pragma unroll
    for (int mt = 0; mt < 4; ++mt)
        #pragma unroll
        for (int i = 0; i < 4; ++i) {
            const int row = row0 + mt * 16 + i;
            const int p = posid[row];
            #pragma unroll
            for (int nt = 0; nt < 4; ++nt) {
                const int g = tn * 128 + wn + nt * 16;   // 16-aligned group base
                const int h = g / 192;
                const int dg = g - h * 192;
                float v = acc[mt][nt][i];
                u16* qr = query + ((size_t)h * S_LEN + row) * QHEAD;
                if (dg < 128) {
                    qr[dg + r] = f2bf(v * QSCALE_LOG2E);
                } else {
                    float vp = __shfl_xor(v, 1, 64);
                    int ir = (dg + r - 128) >> 1;
                    int odd = r & 1;
                    int co = p * 64 + odd * 32 + ir;
                    float c = cosb[co], s = sinb[co];
                    float res = odd ? (v * c + vp * s) : (v * c - vp * s);
                    qr[(odd ? 160 : 128) + ir] = f2bf(res * QSCALE_LOG2E);
                }
            }
        }
}

// ---------------------------------------------------------------------------
// Flash attention v6: S^T form, intra-block split-kv (2 wave-pairs).
// Block = 256 thr = 2 pairs x 2 waves. q-strip 64; within a pair, wave wp
// owns 32 q-cols (2 n-blocks of 16) — round-3's proven per-wave shape.
// kv-tile 64; pair p handles tiles tk ≡ p (mod 2). LDS 2x40KB -> 2 blocks/CU
// = 8 waves/CU = 2 waves/SIMD. Maxless exp2 softmax => pair partials are
// additive; combined through LDS at the end (no HBM partial traffic).
// ---------------------------------------------------------------------------
__device__ __forceinline__ void kv_step6(
    const u16* __restrict__ Kl, const u16* __restrict__ Vl,
    const bf16x8 (&Qf)[2][6], f32x4 (&Oacc)[8][2], float (&lsum)[2],
    int lane, int quad, int r, int kglob0, int qg0, int qg1, bool maskT)
{
    f32x4 Sacc[4][2];
    #pragma unroll
    for (int mtk = 0; mtk < 4; ++mtk) {
        Sacc[mtk][0] = (f32x4){0.f, 0.f, 0.f, 0.f};
        Sacc[mtk][1] = (f32x4){0.f, 0.f, 0.f, 0.f};
    }
    #pragma unroll
    for (int kc = 0; kc < 6; ++kc)
        #pragma unroll
        for (int mtk = 0; mtk < 4; ++mtk) {
            bf16x8 Ak = *(const bf16x8*)&Kl[(mtk * 6 + kc) * 512 + lane * 8];
            Sacc[mtk][0] = __builtin_amdgcn_mfma_f32_16x16x32_bf16(
                Ak, Qf[0][kc], Sacc[mtk][0], 0, 0, 0);
            Sacc[mtk][1] = __builtin_amdgcn_mfma_f32_16x16x32_bf16(
                Ak, Qf[1][kc], Sacc[mtk][1], 0, 0, 0);
        }
    #pragma unroll
    for (int kb = 0; kb < 4; ++kb) {
        s16x4 Pf[2];
        const int kb0 = kglob0 + kb * 16 + quad * 4;
        #pragma unroll
        for (int n = 0; n < 2; ++n) {
            const int qg = n ? qg1 : qg0;
            #pragma unroll
            for (int i = 0; i < 4; ++i) {
                float p = exp2f(Sacc[kb][n][i]);
                if (maskT && (kb0 + i > qg)) p = 0.f;
                lsum[n] += p;
                Pf[n][i] = (short)f2bf(p);
            }
        }
        #pragma unroll
        for (int mtd = 0; mtd < 8; ++mtd) {
            s16x4 Av = *(const s16x4*)&Vl[(mtd * 2 + (kb >> 1)) * 512
                         + ((kb & 1) * 2 + (quad >> 1)) * 128 + r * 8 + (quad & 1) * 4];
            Oacc[mtd][0] = mfma16(Av, Pf[0], Oacc[mtd][0]);
            Oacc[mtd][1] = mfma16(Av, Pf[1], Oacc[mtd][1]);
        }
    }
}

__global__ __launch_bounds__(256, 1)
void flash_attn(const u16* __restrict__ query, const u16* __restrict__ kvb,
                const u16* __restrict__ kpe, const u16* __restrict__ vt,
                u16* __restrict__ ao)
{
    const int tid = threadIdx.x;
    const int w = tid >> 6, lane = tid & 63;
    const int p = w >> 1, wp = w & 1;
    const int quad = lane >> 4, r = lane & 15;
    const int j = 31 - (int)blockIdx.x;   // heavy strips first
    const int h = blockIdx.y;
    const int q0 = j * 64;
    const int ntk = j + 1;                // 64-wide kv-tiles
    const int nIt = (ntk + 1) >> 1;       // per-pair steps (barrier-matched)

    // per-pair region: K 24 chunks (24KB) + V 16 chunks (16KB) = 40KB
    __shared__ __align__(16) u16 Sh[2][20480];
    u16* Kl = Sh[p];
    u16* Vl = Sh[p] + 12288;

    const int qg0 = q0 + wp * 32 + r;
    const int qg1 = qg0 + 16;

    bf16x8 Qf[2][6];
    #pragma unroll
    for (int n = 0; n < 2; ++n)
        #pragma unroll
        for (int kc = 0; kc < 6; ++kc)
            Qf[n][kc] = *(const bf16x8*)(query
                + ((size_t)h * S_LEN + q0 + wp * 32 + n * 16 + r) * QHEAD
                + kc * 32 + quad * 8);

    f32x4 Oacc[8][2];
    #pragma unroll
    for (int mtd = 0; mtd < 8; ++mtd) {
        Oacc[mtd][0] = (f32x4){0.f, 0.f, 0.f, 0.f};
        Oacc[mtd][1] = (f32x4){0.f, 0.f, 0.f, 0.f};
    }
    float lsum[2] = {0.f, 0.f};

    for (int it = 0; it < nIt; ++it) {
        const int tk = 2 * it + p;
        const bool act = tk < ntk;
        if (act) {
            if (wp == 0) {
                #pragma unroll
                for (int g = 0; g < 20; ++g) {   // K chunks 0..19
                    int mtk = g / 6, kc = g % 6;
                    int row = tk * 64 + mtk * 16 + r;
                    const u16* src = (kc < 4)
                        ? kvb + (size_t)row * 4096 + h * 256 + kc * 32 + quad * 8
                        : kpe + (size_t)row * 64 + (kc - 4) * 32 + quad * 8;
                    gl_lds16(src, &Kl[g * 512]);
                }
            } else {
                #pragma unroll
                for (int g = 20; g < 24; ++g) {  // K chunks 20..23
                    int mtk = g / 6, kc = g % 6;
                    int row = tk * 64 + mtk * 16 + r;
                    const u16* src = (kc < 4)
                        ? kvb + (size_t)row * 4096 + h * 256 + kc * 32 + quad * 8
                        : kpe + (size_t)row * 64 + (kc - 4) * 32 + quad * 8;
                    gl_lds16(src, &Kl[g * 512]);
                }
                #pragma unroll
                for (int cv = 0; cv < 16; ++cv) { // V chunks
                    int mtd = cv >> 1, sc = cv & 1;
                    const u16* src = vt + ((size_t)h * 128 + mtd * 16 + r) * 2048
                                     + tk * 64 + sc * 32 + quad * 8;
                    gl_lds16(src, &Vl[cv * 512]);
                }
            }
        }
        __syncthreads();
        if (act)
            kv_step6(Kl, Vl, Qf, Oacc, lsum, lane, quad, r, tk * 64, qg0, qg1, tk == j);
        __syncthreads();
    }

    // quad-reduce l (bits 4..5 of lane index the quad)
    #pragma unroll
    for (int n = 0; n < 2; ++n) {
        lsum[n] += __shfl_xor(lsum[n], 16, 64);
        lsum[n] += __shfl_xor(lsum[n], 32, 64);
    }

    // combine pair partials through LDS (pair 1's region is dead now)
    f32x4* Po = (f32x4*)&Sh[1][0];           // 2048 f32x4 = 32KB
    float*  Pl = (float*)&Sh[1][16384];      // 64 floats
    if (p == 1) {
        #pragma unroll
        for (int n = 0; n < 2; ++n) {
            #pragma unroll
            for (int mtd = 0; mtd < 8; ++mtd)
                Po[((n * 8 + mtd) * 2 + wp) * 64 + lane] = Oacc[mtd][n];
            if (quad == 0) Pl[(n * 2 + wp) * 16 + r] = lsum[n];
        }
    }
    __syncthreads();
    if (p == 0) {
        #pragma unroll
        for (int n = 0; n < 2; ++n) {
            float l = lsum[n] + Pl[(n * 2 + wp) * 16 + r];
            float inv = 1.0f / l;
            const int qrow = q0 + wp * 32 + n * 16 + r;
            #pragma unroll
            for (int mtd = 0; mtd < 8; ++mtd) {
                f32x4 o = Oacc[mtd][n] + Po[((n * 8 + mtd) * 2 + wp) * 64 + lane];
                ushort4 ov;
                ov.x = f2bf(o[0] * inv); ov.y = f2bf(o[1] * inv);
                ov.z = f2bf(o[2] * inv); ov.w = f2bf(o[3] * inv);
                *(ushort4*)(ao + (size_t)qrow * 2048 + h * 128 + mtd * 16 + quad * 4) = ov;
            }
        }
    }
}

// ---------------------------------------------------------------------------
__global__ __launch_bounds__(256)
void cvt_f32_bf16(const float4* __restrict__ in, ushort4* __restrict__ out, int n4)
{
    int i = blockIdx.x * 256 + threadIdx.x;
    if (i < n4) {
        float4 v = in[i];
        ushort4 o;
        o.x = f2bf(v.x); o.y = f2bf(v.y); o.z = f2bf(v.z); o.w = f2bf(v.w);
        out[i] = o;
    }
}

// all 5 weight transposes in one dispatch. fp32 [K][N] -> bf16 [Npad][K].
struct WT5 {
    const float* src[5];
    u16* dst[5];
    int K[5], Np[5], N[5], start[6];
};
__global__ __launch_bounds__(256)
void wtrans_multi(WT5 t)
{
    __shared__ float tile[32][33];
    int bid = blockIdx.x;
    int seg = 0;
    #pragma unroll
    for (int s = 0; s < 5; ++s)
        if (bid >= t.start[s]) seg = s;
    int local = bid - t.start[seg];
    int ntn = t.Np[seg] >> 5;
    int kt = local / ntn, nt = local - kt * ntn;
    const float* in = t.src[seg];
    u16* out = t.dst[seg];
    int K = t.K[seg], N = t.N[seg];
    int k0 = kt * 32, n0 = nt * 32;
    int tx = threadIdx.x, ty = threadIdx.y;
    #pragma unroll
    for (int jj = 0; jj < 32; jj += 8) {
        int n = n0 + tx;
        tile[ty + jj][tx] = (n < N) ? in[(long)(k0 + ty + jj) * N + n] : 0.0f;
    }
    __syncthreads();
    #pragma unroll
    for (int jj = 0; jj < 32; jj += 8)
        out[(long)(n0 + ty + jj) * K + k0 + tx] = f2bf(tile[tx][ty + jj]);
}

// fused: RMS-norm q_a (cols 0..1535, in place) + RMS-norm c (cols 1536..2047
// -> kvout fp32 / cnb bf16) + k_pe rope (cols 2048..2111 -> kvout / kpe).
__global__ __launch_bounds__(256)
void norm_fused(u16* __restrict__ qkv, const float* __restrict__ q_ln,
                const float* __restrict__ kv_ln, const int* __restrict__ pos_ids,
                const float* __restrict__ cosb, const float* __restrict__ sinb,
                float* __restrict__ kvout, u16* __restrict__ cnb,
                u16* __restrict__ kpe)
{
    const int s = blockIdx.x, tid = threadIdx.x;
    u16* row = qkv + (size_t)s * 2176;
    __shared__ float red1[4], red2[4];
    float s1 = 0.f, s2 = 0.f;
    for (int d = tid; d < 2048; d += 256) {
        float v = bf2f(row[d]); float v2 = v * v;
        if (d < 1536) s1 += v2; else s2 += v2;
    }
    #pragma unroll
    for (int o = 32; o; o >>= 1) { s1 += __shfl_xor(s1, o, 64); s2 += __shfl_xor(s2, o, 64); }
    if ((tid & 63) == 0) { red1[tid >> 6] = s1; red2[tid >> 6] = s2; }
    __syncthreads();
    s1 = red1[0] + red1[1] + red1[2] + red1[3];
    s2 = red2[0] + red2[1] + red2[2] + red2[3];
    const float sc1 = rsqrtf(s1 / 1536.f + EPS);
    const float sc2 = rsqrtf(s2 / 512.f + EPS);
    for (int d = tid; d < 1536; d += 256)
        row[d] = f2bf(bf2f(row[d]) * sc1 * q_ln[d]);
    for (int d = tid; d < 512; d += 256) {
        float v = bf2f(row[1536 + d]) * sc2 * kv_ln[d];
        kvout[(size_t)s * 576 + d] = v;
        cnb[(size_t)s * 512 + d] = f2bf(v);
    }
    if (tid < 32) {
        int p = pos_ids[s];
        float x0 = bf2f(row[2048 + 2 * tid]);
        float x1 = bf2f(row[2048 + 2 * tid + 1]);
        float c1 = cosb[p * 64 + tid], sn1 = sinb[p * 64 + tid];
        float c2 = cosb[p * 64 + 32 + tid], sn2 = sinb[p * 64 + 32 + tid];
        float lo = x0 * c1 - x1 * sn1;
        float hi = x1 * c2 + x0 * sn2;
        kvout[(size_t)s * 576 + 512 + tid] = lo;
        kvout[(size_t)s * 576 + 544 + tid] = hi;
        kpe[(size_t)s * 64 + tid] = f2bf(lo);
        kpe[(size_t)s * 64 + 32 + tid] = f2bf(hi);
    }
}

// kv bf16 [S][4096] value part -> vt bf16 [H*128][S] (transposed)
__global__ __launch_bounds__(256)
void vtrans_k(const u16* __restrict__ kv, u16* __restrict__ vt)
{
    __shared__ u16 tile[32][33];
    int s0 = blockIdx.x * 32, d0 = blockIdx.y * 32, h = blockIdx.z;
    int tx = threadIdx.x, ty = threadIdx.y;
    #pragma unroll
    for (int jj = 0; jj < 32; jj += 8)
        tile[ty + jj][tx] = kv[(long)(s0 + ty + jj) * 4096 + h * 256 + 128 + d0 + tx];
    __syncthreads();
    #pragma unroll
    for (int jj = 0; jj < 32; jj += 8)
        vt[(long)(h * 128 + d0 + ty + jj) * S_LEN + s0 + tx] = tile[tx][ty + jj];
}

// ---------------------------------------------------------------------------
extern "C" void kernel_launch(void* const* d_in, const int* in_sizes, int n_in,
                              void* d_out, int out_size, void* d_ws, size_t ws_size,
                              hipStream_t stream)
{
    const float* x      = (const float*)d_in[0];
    const int*   posid  = (const int*)d_in[2];
    const float* cosb   = (const float*)d_in[3];
    const float* sinb   = (const float*)d_in[4];
    const float* q_a_w  = (const float*)d_in[5];
    const float* q_a_ln = (const float*)d_in[6];
    const float* q_b_w  = (const float*)d_in[7];
    const float* kv_a_w = (const float*)d_in[8];
    const float* kv_a_ln= (const float*)d_in[9];
    const float* kv_b_w = (const float*)d_in[10];
    const float* o_w    = (const float*)d_in[11];

    float* out    = (float*)d_out;
    float* kv_out = out + (size_t)2048 * 2048;

    char* ws = (char*)d_ws;
    size_t off = 0;
    auto alloc = [&](size_t bytes) { char* p = ws + off; off += (bytes + 255) & ~(size_t)255; return p; };
    u16* owt   = (u16*)alloc(2048ULL * 2048 * 2);
    u16* query = (u16*)alloc(16ULL * 2048 * 192 * 2);
    u16* kpe   = (u16*)alloc(2048ULL * 64 * 2);
    u16* kvbuf = (u16*)alloc(2048ULL * 4096 * 2);
    u16* vt    = (u16*)alloc(16ULL * 128 * 2048 * 2);
    u16* ao    = (u16*)alloc(2048ULL * 2048 * 2);
    u16* xb    = (u16*)alloc(2048ULL * 2048 * 2);
    u16* W1    = (u16*)alloc(2176ULL * 2048 * 2);   // [q_a^T ; kv_a^T(pad 640)]
    u16* qbwt  = (u16*)alloc(3072ULL * 1536 * 2);
    u16* kvbwt = (u16*)alloc(4096ULL * 512 * 2);
    u16* qkv_a = (u16*)alloc(2048ULL * 2176 * 2);   // [q_a(1536) | ckv(640)]
    u16* cnb   = (u16*)alloc(2048ULL * 512 * 2);
    (void)ws_size; (void)in_sizes; (void)n_in; (void)out_size;

    dim3 blk(256);
    dim3 tblk(32, 8);

    // 0) input convert + all weight transposes (one dispatch)
    cvt_f32_bf16<<<dim3(4096), blk, 0, stream>>>((const float4*)x, (ushort4*)xb, 2048 * 2048 / 4);
    WT5 t;
    t.src[0] = q_a_w;  t.dst[0] = W1;                  t.K[0] = 2048; t.Np[0] = 1536; t.N[0] = 1536;
    t.src[1] = kv_a_w; t.dst[1] = W1 + 1536ULL * 2048; t.K[1] = 2048; t.Np[1] = 640;  t.N[1] = 576;
    t.src[2] = q_b_w;  t.dst[2] = qbwt;                t.K[2] = 1536; t.Np[2] = 3072; t.N[2] = 3072;
    t.src[3] = kv_b_w; t.dst[3] = kvbwt;               t.K[3] = 512;  t.Np[3] = 4096; t.N[3] = 4096;
    t.src[4] = o_w;    t.dst[4] = owt;                 t.K[4] = 2048; t.Np[4] = 2048; t.N[4] = 2048;
    t.start[0] = 0;
    t.start[1] = t.start[0] + (2048 / 32) * (1536 / 32);
    t.start[2] = t.start[1] + (2048 / 32) * (640 / 32);
    t.start[3] = t.start[2] + (1536 / 32) * (3072 / 32);
    t.start[4] = t.start[3] + (512 / 32) * (4096 / 32);
    t.start[5] = t.start[4] + (2048 / 32) * (2048 / 32);
    wtrans_multi<<<dim3(t.start[5]), tblk, 0, stream>>>(t);

    // 1) [q_a | ckv] = x @ [q_a_w | kv_a_w]; fused norms + k_pe rope
    gemm_bt<0><<<dim3(17, 16), blk, 0, stream>>>(xb, W1, qkv_a, 2048, 2048, 2048, 2176);
    norm_fused<<<dim3(2048), blk, 0, stream>>>(qkv_a, q_a_ln, kv_a_ln, posid, cosb, sinb,
                                               kv_out, cnb, kpe);

    // 2) q = q_a_norm @ q_b_w with fused rope/relayout/scale -> query
    gemm_qrope<<<dim3(24, 16), blk, 0, stream>>>(qkv_a, qbwt, query, posid, cosb, sinb);

    // 3) kv = c_norm @ kv_b_w ; transpose value
    gemm_bt<0><<<dim3(32, 16), blk, 0, stream>>>(cnb, kvbwt, kvbuf, 512, 512, 512, 4096);
    vtrans_k<<<dim3(64, 4, 16), tblk, 0, stream>>>(kvbuf, vt);

    // 4) flash attention (intra-block split-kv) -> ao bf16 [S][H*128]
    flash_attn<<<dim3(32, 16), blk, 0, stream>>>(query, kvbuf, kpe, vt, ao);

    // 5) out = ao @ o_w (fp32)
    gemm_bt<1><<<dim3(16, 16), blk, 0, stream>>>(ao, owt, out, 2048, 2048, 2048, 2048);
}